// Round 13
// baseline (202.054 us; speedup 1.0000x reference)
//
#include <hip/hip_runtime.h>
#include <hip/hip_bf16.h>
#include <stdint.h>

#define NNODES 4096
#define NHEADS 4
#define CAP 192   // max neighbors kept per row (deg ~42, binomial tail << 192)

typedef short s16x8 __attribute__((ext_vector_type(8)));
typedef float f32x4 __attribute__((ext_vector_type(4)));
typedef unsigned int u32x4 __attribute__((ext_vector_type(4)));

typedef const __attribute__((address_space(1))) unsigned short* gas_ushort_p;
typedef __attribute__((address_space(3))) unsigned short* las_ushort_p;

__device__ __forceinline__ unsigned short f2bf(float f) {
  unsigned u = __builtin_bit_cast(unsigned, f);
  u += 0x7FFFu + ((u >> 16) & 1u);   // RNE
  return (unsigned short)(u >> 16);
}
__device__ __forceinline__ float bf2f(unsigned short s) {
  return __builtin_bit_cast(float, ((unsigned)s) << 16);
}
// pack two f32 -> (bf16 lo, bf16 hi)  [guide T12 recipe: no builtin on gfx950]
__device__ __forceinline__ unsigned cvt_pk_bf16(float lo, float hi) {
  unsigned r;
  asm("v_cvt_pk_bf16_f32 %0, %1, %2" : "=v"(r) : "v"(lo), "v"(hi));
  return r;
}
// acc += a.bf16[0]*b.bf16[0] + a.bf16[1]*b.bf16[1]   (VOP3P v_dot2_f32_bf16)
__device__ __forceinline__ float dot2bf(unsigned a, unsigned b, float c) {
  asm("v_dot2_f32_bf16 %0, %1, %2, %0" : "+v"(c) : "v"(a), "v"(b));
  return c;
}

// ================= fused prep: CSR build + cast + 3x weight transpose =================
__global__ __launch_bounds__(256) void k_prep(const float* __restrict__ adj,
                                              int* __restrict__ csr, int* __restrict__ cnt,
                                              const float* __restrict__ node_feats,
                                              unsigned short* __restrict__ x0,
                                              const float* __restrict__ W0,
                                              unsigned short* __restrict__ Wt0,
                                              const float* __restrict__ W1,
                                              unsigned short* __restrict__ Wt1,
                                              const float* __restrict__ W2,
                                              unsigned short* __restrict__ Wt2) {
  __shared__ int wcnt[4];
  __shared__ unsigned short t[64][65];
  const int bid = blockIdx.x;
  const int tid = threadIdx.x;

  if (bid < 4096) {
    // ---- CSR build: one block per row, two-phase ----
    const int row = bid;
    const int wid = tid >> 6;
    const int lane = tid & 63;
    const float4* ar = (const float4*)(adj + (size_t)row * NNODES);
    int* crow = csr + row * CAP;
    const unsigned long long below = (1ull << lane) - 1ull;

    float4 v[4];
#pragma unroll
    for (int it = 0; it < 4; ++it) v[it] = ar[wid * 256 + it * 64 + lane];

    unsigned long long b[4][4];
    int wtotal = 0;
#pragma unroll
    for (int it = 0; it < 4; ++it) {
      b[it][0] = __ballot(v[it].x > 0.f);
      b[it][1] = __ballot(v[it].y > 0.f);
      b[it][2] = __ballot(v[it].z > 0.f);
      b[it][3] = __ballot(v[it].w > 0.f);
      wtotal += __popcll(b[it][0]) + __popcll(b[it][1]) + __popcll(b[it][2]) + __popcll(b[it][3]);
    }
    if (lane == 0) wcnt[wid] = wtotal;
    __syncthreads();

    int base = 0;
#pragma unroll
    for (int w = 0; w < 4; ++w) base += (w < wid) ? wcnt[w] : 0;

#pragma unroll
    for (int it = 0; it < 4; ++it) {
      int pre = __popcll(b[it][0] & below) + __popcll(b[it][1] & below) +
                __popcll(b[it][2] & below) + __popcll(b[it][3] & below);
      int col0 = wid * 1024 + it * 256 + lane * 4;
      int pos = base + pre;
      if (v[it].x > 0.f) { if (pos < CAP) crow[pos] = col0;     ++pos; }
      if (v[it].y > 0.f) { if (pos < CAP) crow[pos] = col0 + 1; ++pos; }
      if (v[it].z > 0.f) { if (pos < CAP) crow[pos] = col0 + 2; ++pos; }
      if (v[it].w > 0.f) { if (pos < CAP) crow[pos] = col0 + 3; ++pos; }
      base += __popcll(b[it][0]) + __popcll(b[it][1]) + __popcll(b[it][2]) + __popcll(b[it][3]);
    }
    if (tid == 0) {
      int total = wcnt[0] + wcnt[1] + wcnt[2] + wcnt[3];
      cnt[row] = total < CAP ? total : CAP;
    }
    return;
  }

  if (bid < 6144) {
    // ---- node_feats f32 -> bf16 ----
    int i = (bid - 4096) * 256 + tid;
    float4 v = ((const float4*)node_feats)[i];
    ushort4 o;
    o.x = f2bf(v.x); o.y = f2bf(v.y); o.z = f2bf(v.z); o.w = f2bf(v.w);
    ((ushort4*)x0)[i] = o;
    return;
  }

  // ---- W [H][K][F] f32 -> Wt [H*F][K] bf16, 64x64 tiles ----
  const float* W;
  unsigned short* Wt;
  int K, F, idx;
  if (bid < 6400) { W = W0; Wt = Wt0; K = 512;  F = 512; idx = bid - 6144; }
  else if (bid < 7424) { W = W1; Wt = Wt1; K = 2048; F = 512; idx = bid - 6400; }
  else { W = W2; Wt = Wt2; K = 2048; F = 64; idx = bid - 7424; }
  const int nk = K >> 6, nf = F >> 6;
  const int h = idx / (nk * nf);
  const int rem = idx % (nk * nf);
  const int kt = rem / nf, ft = rem % nf;
  const float* Wp = W + (size_t)h * K * F;
  for (int it = 0; it < 16; ++it) {
    int j = it * 256 + tid;
    int r = j >> 6, c = j & 63;
    t[c][r] = f2bf(Wp[(size_t)(kt * 64 + r) * F + ft * 64 + c]);
  }
  __syncthreads();
  for (int it = 0; it < 16; ++it) {
    int j = it * 256 + tid;
    int c = j >> 6, r = j & 63;
    Wt[(size_t)(h * F + ft * 64 + c) * K + kt * 64 + r] = t[c][r];
  }
}

// ======== pipelined GEMM, 128x256 tile (M x N), 512 threads / 8 waves (2M x 4N) ========
// Higher arithmetic intensity: 48 KB staged per 4.2 MFLOP (87 FLOP/B vs 65 at 128^2).
// Grid = (M/128)*(N/256) = 256 blocks = 1/CU. dbuf LDS 96 KB. 6 loads/thread/tile
// (2 A + 4 B) -> counted vmcnt(6), never drains mid-loop. Wave tile 64x64, acc[4][4].
// FUSE_F: butterfly transpose-reduce f-partials; slot (tn*4+wn), 8 per head.
template <bool F32OUT, bool FUSE_F>
__device__ __forceinline__ void gemm_body(const unsigned short* __restrict__ A,
                                          const unsigned short* __restrict__ B,
                                          void* __restrict__ Cv,
                                          const float* __restrict__ avec,
                                          float* __restrict__ fps, float* __restrict__ fpd,
                                          int N, int K, int tm, int tn, int k0, int nkt,
                                          unsigned short* sA0, unsigned short* sB0) {
  unsigned short (*sA)[128 * 64] = (unsigned short(*)[128 * 64])sA0;
  unsigned short (*sB)[256 * 64] = (unsigned short(*)[256 * 64])sB0;
  const int tid = threadIdx.x;
  const int lane = tid & 63;
  const int wave = tid >> 6;          // 0..7
  const int wm = wave >> 2;           // 0..1 (64-row half of 128)
  const int wn = wave & 3;            // 0..3 (64-col quarter of 256)

  f32x4 acc[4][4];
#pragma unroll
  for (int i = 0; i < 4; ++i)
#pragma unroll
    for (int j = 0; j < 4; ++j) acc[i][j] = (f32x4){0.f, 0.f, 0.f, 0.f};

  int soffA[2], loffA[2];             // A: 1024 chunks of 16B, 2/thread
  int soffB[4], loffB[4];             // B: 2048 chunks of 16B, 4/thread
#pragma unroll
  for (int it = 0; it < 2; ++it) {
    int cid = it * 512 + tid;
    int r = cid >> 3, cb = cid & 7;
    soffA[it] = r * K + ((cb ^ (r & 7)) << 3);  // pre-swizzled global source (ushorts)
    loffA[it] = cid << 3;                       // linear LDS dest (ushorts)
  }
#pragma unroll
  for (int it = 0; it < 4; ++it) {
    int cid = it * 512 + tid;
    int r = cid >> 3, cb = cid & 7;
    soffB[it] = r * K + ((cb ^ (r & 7)) << 3);
    loffB[it] = cid << 3;
  }
  const unsigned short* Ab = A + (size_t)tm * 128 * K + k0;
  const unsigned short* Bb = B + (size_t)tn * 256 * K + k0;

  auto stage = [&](int slot, int ko) {
    const unsigned short* Ag = Ab + (ko << 6);
    const unsigned short* Bg = Bb + (ko << 6);
#pragma unroll
    for (int it = 0; it < 2; ++it)
      __builtin_amdgcn_global_load_lds((gas_ushort_p)(Ag + soffA[it]),
                                       (las_ushort_p)(&sA[slot][0]) + loffA[it], 16, 0, 0);
#pragma unroll
    for (int it = 0; it < 4; ++it)
      __builtin_amdgcn_global_load_lds((gas_ushort_p)(Bg + soffB[it]),
                                       (las_ushort_p)(&sB[slot][0]) + loffB[it], 16, 0, 0);
  };

  auto compute = [&](int slot) {
#pragma unroll
    for (int kk = 0; kk < 2; ++kk) {
      s16x8 af[4], bfr[4];
#pragma unroll
      for (int mi = 0; mi < 4; ++mi) {
        int r = wm * 64 + mi * 16 + (lane & 15);
        int kb = (kk << 6) + ((lane >> 4) << 4);
        af[mi] = *(const s16x8*)((const char*)&sA[slot][0] + r * 128 + (kb ^ ((r & 7) << 4)));
      }
#pragma unroll
      for (int ni = 0; ni < 4; ++ni) {
        int r = wn * 64 + ni * 16 + (lane & 15);
        int kb = (kk << 6) + ((lane >> 4) << 4);
        bfr[ni] = *(const s16x8*)((const char*)&sB[slot][0] + r * 128 + (kb ^ ((r & 7) << 4)));
      }
      __builtin_amdgcn_s_setprio(1);
#pragma unroll
      for (int mi = 0; mi < 4; ++mi)
#pragma unroll
        for (int ni = 0; ni < 4; ++ni)
          acc[mi][ni] =
              __builtin_amdgcn_mfma_f32_16x16x32_bf16(af[mi], bfr[ni], acc[mi][ni], 0, 0, 0);
      __builtin_amdgcn_s_setprio(0);
    }
  };

  stage(0, 0);
  if (nkt > 1) stage(1, 1);

  for (int t = 0; t < nkt - 1; ++t) {
    asm volatile("s_waitcnt vmcnt(6)" ::: "memory");   // tile t complete (6 newer in flight)
    __builtin_amdgcn_s_barrier();
    __builtin_amdgcn_sched_barrier(0);
    compute(t & 1);
    __builtin_amdgcn_sched_barrier(0);
    __builtin_amdgcn_s_barrier();
    __builtin_amdgcn_sched_barrier(0);
    if (t + 2 < nkt) stage(t & 1, t + 2);
  }
  asm volatile("s_waitcnt vmcnt(0)" ::: "memory");
  __builtin_amdgcn_s_barrier();
  __builtin_amdgcn_sched_barrier(0);
  compute((nkt - 1) & 1);

  // epilogue: C/D layout col=lane&15, row=(lane>>4)*4+r  [m89-verified]
#pragma unroll
  for (int mi = 0; mi < 4; ++mi) {
    int row0 = tm * 128 + wm * 64 + mi * 16 + ((lane >> 4) << 2);
#pragma unroll
    for (int ni = 0; ni < 4; ++ni) {
      int col = tn * 256 + wn * 64 + ni * 16 + (lane & 15);
#pragma unroll
      for (int r = 0; r < 4; ++r) {
        if constexpr (F32OUT)
          ((float*)Cv)[(size_t)(row0 + r) * N + col] = acc[mi][ni][r];
        else
          ((unsigned short*)Cv)[(size_t)(row0 + r) * N + col] = f2bf(acc[mi][ni][r]);
      }
    }
  }

  if constexpr (FUSE_F) {
    // a[H][2][512]; tile spans 256 cols -> head = tn>>1; wave covers 64 cols.
    const int head = tn >> 1;
    const int cw = (tn & 1) * 256 + wn * 64 + (lane & 15);   // col within head
    float a0v[4], a1v[4];
#pragma unroll
    for (int ni = 0; ni < 4; ++ni) {
      a0v[ni] = avec[head * 1024 + cw + ni * 16];
      a1v[ni] = avec[head * 1024 + 512 + cw + ni * 16];
    }
    float s16v[16], d16v[16];
#pragma unroll
    for (int mi = 0; mi < 4; ++mi)
#pragma unroll
      for (int r = 0; r < 4; ++r) {
        float vs = 0.f, vd = 0.f;
#pragma unroll
        for (int ni = 0; ni < 4; ++ni) {
          float av = acc[mi][ni][r];
          vs += av * a0v[ni];
          vd += av * a1v[ni];
        }
        s16v[mi * 4 + r] = vs;
        d16v[mi * 4 + r] = vd;
      }
    // butterfly transpose-reduce across the 16 col-lanes (lane&15)
    const bool q0 = lane & 1, q1 = lane & 2, q2 = lane & 4, q3 = lane & 8;
    float s8[8], d8[8];
#pragma unroll
    for (int j = 0; j < 8; ++j) {
      float ms = q0 ? s16v[j + 8] : s16v[j], ss = q0 ? s16v[j] : s16v[j + 8];
      s8[j] = ms + __shfl_xor(ss, 1);
      float md = q0 ? d16v[j + 8] : d16v[j], sd = q0 ? d16v[j] : d16v[j + 8];
      d8[j] = md + __shfl_xor(sd, 1);
    }
    float s4[4], d4[4];
#pragma unroll
    for (int j = 0; j < 4; ++j) {
      float ms = q1 ? s8[j + 4] : s8[j], ss = q1 ? s8[j] : s8[j + 4];
      s4[j] = ms + __shfl_xor(ss, 2);
      float md = q1 ? d8[j + 4] : d8[j], sd = q1 ? d8[j] : d8[j + 4];
      d4[j] = md + __shfl_xor(sd, 2);
    }
    float s2v[2], d2v[2];
#pragma unroll
    for (int j = 0; j < 2; ++j) {
      float ms = q2 ? s4[j + 2] : s4[j], ss = q2 ? s4[j] : s4[j + 2];
      s2v[j] = ms + __shfl_xor(ss, 4);
      float md = q2 ? d4[j + 2] : d4[j], sd = q2 ? d4[j] : d4[j + 2];
      d2v[j] = md + __shfl_xor(sd, 4);
    }
    float ms = q3 ? s2v[1] : s2v[0], ss = q3 ? s2v[0] : s2v[1];
    float s1v = ms + __shfl_xor(ss, 8);
    float md = q3 ? d2v[1] : d2v[0], sd = q3 ? d2v[0] : d2v[1];
    float d1v = md + __shfl_xor(sd, 8);
    // lane holds value idx = bitrev4(lane&15)
    int idx = ((lane & 1) << 3) | ((lane & 2) << 1) | ((lane & 4) >> 1) | ((lane & 8) >> 3);
    int row = tm * 128 + wm * 64 + (idx >> 2) * 16 + ((lane >> 4) << 2) + (idx & 3);
    fps[(tn * 4 + wn) * NNODES + row] = s1v;
    fpd[(tn * 4 + wn) * NNODES + row] = d1v;
  }
}

__global__ __launch_bounds__(512, 2) void k_gemm_p(const unsigned short* __restrict__ A,
                                                   const unsigned short* __restrict__ B,
                                                   unsigned short* __restrict__ C,
                                                   const float* __restrict__ avec,
                                                   float* __restrict__ fps,
                                                   float* __restrict__ fpd,
                                                   int M, int N, int K) {
  __shared__ __align__(16) unsigned short sA[2][128 * 64];
  __shared__ __align__(16) unsigned short sB[2][256 * 64];
  const int ntile = N >> 8;
  const int tm = blockIdx.x / ntile, tn = blockIdx.x % ntile;
  gemm_body<false, true>(A, B, C, avec, fps, fpd, N, K, tm, tn, 0, K >> 6,
                         &sA[0][0], &sB[0][0]);
}

// plain (no f-fusion) variant for the non-split-K fallback
__global__ __launch_bounds__(512, 2) void k_gemm_plain(const unsigned short* __restrict__ A,
                                                       const unsigned short* __restrict__ B,
                                                       unsigned short* __restrict__ C,
                                                       int M, int N, int K) {
  __shared__ __align__(16) unsigned short sA[2][128 * 64];
  __shared__ __align__(16) unsigned short sB[2][256 * 64];
  const int ntile = N >> 8;
  const int tm = blockIdx.x / ntile, tn = blockIdx.x % ntile;
  gemm_body<false, false>(A, B, C, nullptr, nullptr, nullptr, N, K, tm, tn, 0, K >> 6,
                          &sA[0][0], &sB[0][0]);
}

// split-K (x4) variant: writes f32 partials to Cp[kc][M][N]
__global__ __launch_bounds__(512, 2) void k_gemm_sk(const unsigned short* __restrict__ A,
                                                    const unsigned short* __restrict__ B,
                                                    float* __restrict__ Cp,
                                                    int M, int N, int K) {
  __shared__ __align__(16) unsigned short sA[2][128 * 64];
  __shared__ __align__(16) unsigned short sB[2][256 * 64];
  const int ntile = N >> 8;
  const int tpk = (M >> 7) * ntile;       // tiles per K-chunk
  const int kc = blockIdx.x / tpk;
  const int rest = blockIdx.x % tpk;
  const int tm = rest / ntile, tn = rest % ntile;
  const int KC = K >> 2;
  gemm_body<true, false>(A, B, Cp + (size_t)kc * M * N, nullptr, nullptr, nullptr,
                         N, K, tm, tn, kc * KC, KC >> 6, &sA[0][0], &sB[0][0]);
}

// reduce f partials: fs[head][n] = sum_{j<8} fps[(head*8+j)][n]
__global__ __launch_bounds__(256) void k_fred(const float* __restrict__ fps,
                                              const float* __restrict__ fpd,
                                              float* __restrict__ fs,
                                              float* __restrict__ fd) {
  int t = blockIdx.x * 256 + threadIdx.x;   // 16384 threads
  int head = t >> 12, n = t & 4095;
  float s = 0.f, d = 0.f;
#pragma unroll
  for (int j = 0; j < 8; ++j) {
    s += fps[(head * 8 + j) * NNODES + n];
    d += fpd[(head * 8 + j) * NNODES + n];
  }
  fs[head * NNODES + n] = s;
  fd[head * NNODES + n] = d;
}

// ---- layer-2 post: reduce 4 split-K partials -> h bf16, and fs/fd from f32 sums ----
__global__ __launch_bounds__(256) void k_l2post(const float* __restrict__ Cp,
                                                unsigned short* __restrict__ h,
                                                const float* __restrict__ a2,
                                                float* __restrict__ fs,
                                                float* __restrict__ fd) {
  const int n = blockIdx.x;
  const int tid = threadIdx.x;
  const int MN = NNODES * 256;
  const int base = n * 256 + tid;
  float s0 = Cp[base], s1 = Cp[base + MN], s2 = Cp[base + 2 * MN], s3 = Cp[base + 3 * MN];
  float s = (s0 + s1) + (s2 + s3);
  h[(size_t)base] = f2bf(s);
  const int head = tid >> 6, lane = tid & 63;
  float vs = s * a2[head * 128 + lane];
  float vd = s * a2[head * 128 + 64 + lane];
#pragma unroll
  for (int off = 32; off; off >>= 1) {
    vs += __shfl_xor(vs, off);
    vd += __shfl_xor(vd, off);
  }
  if (lane == 0) {
    fs[head * NNODES + n] = vs;
    fd[head * NNODES + n] = vd;
  }
}

// ---------------- f_src / f_dst (fallback only, F=64); h is bf16 ----------------
__global__ __launch_bounds__(256) void k_f(const unsigned short* __restrict__ h,
                                           const float* __restrict__ a,
                                           float* __restrict__ fs, float* __restrict__ fd,
                                           int F) {
  const int n = blockIdx.x;
  const int head = threadIdx.x >> 6;
  const int lane = threadIdx.x & 63;
  const unsigned short* hp = h + (size_t)n * (F * 4) + head * F;
  const float* a0 = a + head * 2 * F;
  const float* a1 = a0 + F;
  float x = bf2f(hp[lane]);
  float s0 = x * a0[lane];
  float s1 = x * a1[lane];
#pragma unroll
  for (int off = 32; off; off >>= 1) {
    s0 += __shfl_xor(s0, off);
    s1 += __shfl_xor(s1, off);
  }
  if (lane == 0) {
    fs[head * NNODES + n] = s0;
    fd[head * NNODES + n] = s1;
  }
}

// ------- sparse softmax + aggregate, F=512, XCD-pinned heads, 16-deep gather -------
__global__ __launch_bounds__(256) void k_agg512(const unsigned short* __restrict__ h,
                                                const float* __restrict__ fs,
                                                const float* __restrict__ fd,
                                                const int* __restrict__ csr,
                                                const int* __restrict__ cnt,
                                                unsigned short* __restrict__ xout) {
  const int g = blockIdx.x >> 3;
  const int x8 = blockIdx.x & 7;
  const int head = x8 >> 1;               // XCD pair -> head
  const int ng = g * 2 + (x8 & 1);        // 0..1023
  const int wid = threadIdx.x >> 6;
  const int lane = threadIdx.x & 63;
  const int n = ng * 4 + wid;
  __shared__ __align__(16) float ws[4][CAP];   // unnormalized softmax weights
  __shared__ __align__(16) int os[4][CAP];     // neighbor row byte offsets (m<<12)
  const int deg = cnt[n];
  const int deg16 = (deg + 15) & ~15;
  const int* nbr = csr + n * CAP;
  const float fsv = fs[head * NNODES + n];
  const float* fdh = fd + head * NNODES;

  // ---- softmax phase: up to 3 edges per lane in registers ----
  float p[3];
  int mm[3];
  float mx = -1e30f;
#pragma unroll
  for (int r = 0; r < 3; ++r) {
    int j = lane + r * 64;
    bool valid = j < deg;
    mm[r] = valid ? nbr[j] : 0;
    float s = fsv + fdh[mm[r]];
    s = s > 0.f ? s : 0.2f * s;  // leaky_relu(0.2)
    p[r] = valid ? s : -1e30f;
    mx = fmaxf(mx, p[r]);
  }
#pragma unroll
  for (int off = 32; off; off >>= 1) mx = fmaxf(mx, __shfl_xor(mx, off));
  float sum = 0.f;
#pragma unroll
  for (int r = 0; r < 3; ++r) {
    int j = lane + r * 64;
    float pv = (j < deg) ? __expf(p[r] - mx) : 0.f;
    sum += pv;
    if (j < deg16) {            // zero-pad up to deg16 (row 0, weight 0)
      ws[wid][j] = pv;
      os[wid][j] = mm[r] << 12;  // row byte offset in h (2048 ushorts = 4096 B)
    }
  }
#pragma unroll
  for (int off = 32; off; off >>= 1) sum += __shfl_xor(sum, off);
  const float inv = 1.f / sum;  // folded into epilogue

  // ---- gather phase: 16 rows in flight, perm+dot2 row-pairs ----
  float acc[8];
#pragma unroll
  for (int i = 0; i < 8; ++i) acc[i] = 0.f;
  const char* hb = (const char*)(h + head * 512) + lane * 16;  // head's 1KB segment

  for (int jb = 0; jb < deg16; jb += 16) {
    float4 w0 = *(const float4*)&ws[wid][jb];
    float4 w1 = *(const float4*)&ws[wid][jb + 4];
    float4 w2 = *(const float4*)&ws[wid][jb + 8];
    float4 w3 = *(const float4*)&ws[wid][jb + 12];
    int4 o0 = *(const int4*)&os[wid][jb];
    int4 o1 = *(const int4*)&os[wid][jb + 4];
    int4 o2 = *(const int4*)&os[wid][jb + 8];
    int4 o3 = *(const int4*)&os[wid][jb + 12];
    u32x4 v[16];
    v[0]  = *(const u32x4*)(hb + o0.x);
    v[1]  = *(const u32x4*)(hb + o0.y);
    v[2]  = *(const u32x4*)(hb + o0.z);
    v[3]  = *(const u32x4*)(hb + o0.w);
    v[4]  = *(const u32x4*)(hb + o1.x);
    v[5]  = *(const u32x4*)(hb + o1.y);
    v[6]  = *(const u32x4*)(hb + o1.z);
    v[7]  = *(const u32x4*)(hb + o1.w);
    v[8]  = *(const u32x4*)(hb + o2.x);
    v[9]  = *(const u32x4*)(hb + o2.y);
    v[10] = *(const u32x4*)(hb + o2.z);
    v[11] = *(const u32x4*)(hb + o2.w);
    v[12] = *(const u32x4*)(hb + o3.x);
    v[13] = *(const u32x4*)(hb + o3.y);
    v[14] = *(const u32x4*)(hb + o3.z);
    v[15] = *(const u32x4*)(hb + o3.w);
    unsigned pw[8];
    pw[0] = cvt_pk_bf16(w0.x, w0.y);
    pw[1] = cvt_pk_bf16(w0.z, w0.w);
    pw[2] = cvt_pk_bf16(w1.x, w1.y);
    pw[3] = cvt_pk_bf16(w1.z, w1.w);
    pw[4] = cvt_pk_bf16(w2.x, w2.y);
    pw[5] = cvt_pk_bf16(w2.z, w2.w);
    pw[6] = cvt_pk_bf16(w3.x, w3.y);
    pw[7] = cvt_pk_bf16(w3.z, w3.w);
#pragma unroll
    for (int rp = 0; rp < 8; ++rp) {
      u32x4 a = v[2 * rp], b = v[2 * rp + 1];
      unsigned wp = pw[rp];
#pragma unroll
      for (int q = 0; q < 4; ++q) {
        unsigned lo = __builtin_amdgcn_perm(b[q], a[q], 0x05040100u);
        unsigned hi = __builtin_amdgcn_perm(b[q], a[q], 0x07060302u);
        acc[2 * q] = dot2bf(wp, lo, acc[2 * q]);
        acc[2 * q + 1] = dot2bf(wp, hi, acc[2 * q + 1]);
      }
    }
  }

  s16x8 o;
#pragma unroll
  for (int i = 0; i < 8; ++i) {
    float v = acc[i] * inv;
    v = v > 0.f ? v : (__expf(v) - 1.f);  // per-layer ELU
    o[i] = (short)f2bf(v);
  }
  *(s16x8*)(xout + (size_t)n * 2048 + head * 512 + lane * 8) = o;
}

// ---------------- final layer aggregate (F=64) + double ELU, f32 out ----------------
__global__ __launch_bounds__(256) void k_agg64(const unsigned short* __restrict__ h,
                                               const float* __restrict__ fs,
                                               const float* __restrict__ fd,
                                               const int* __restrict__ csr,
                                               const int* __restrict__ cnt,
                                               float* __restrict__ fout) {
  const int n = blockIdx.x;
  const int head = threadIdx.x >> 6;
  const int lane = threadIdx.x & 63;
  __shared__ float w[NHEADS][CAP];
  const int deg = cnt[n];
  const int* nbr = csr + n * CAP;
  const float fsv = fs[head * NNODES + n];
  const float* fdh = fd + head * NNODES;

  float mx = -1e30f;
  for (int j = lane; j < deg; j += 64) {
    float s = fsv + fdh[nbr[j]];
    s = s > 0.f ? s : 0.2f * s;
    w[head][j] = s;
    mx = fmaxf(mx, s);
  }
#pragma unroll
  for (int off = 32; off; off >>= 1) mx = fmaxf(mx, __shfl_xor(mx, off));
  float sum = 0.f;
  for (int j = lane; j < deg; j += 64) {
    float pv = __expf(w[head][j] - mx);
    w[head][j] = pv;
    sum += pv;
  }
#pragma unroll
  for (int off = 32; off; off >>= 1) sum += __shfl_xor(sum, off);
  const float inv = 1.f / sum;

  float acc = 0.f;
  const unsigned short* hb = h + head * 64 + lane;
  int j = 0;
  for (; j + 3 < deg; j += 4) {
    int m0 = nbr[j], m1 = nbr[j + 1], m2 = nbr[j + 2], m3 = nbr[j + 3];
    float w0 = w[head][j], w1 = w[head][j + 1], w2 = w[head][j + 2], w3 = w[head][j + 3];
    acc += w0 * bf2f(hb[(size_t)m0 * 256]) + w1 * bf2f(hb[(size_t)m1 * 256]) +
           w2 * bf2f(hb[(size_t)m2 * 256]) + w3 * bf2f(hb[(size_t)m3 * 256]);
  }
  for (; j < deg; ++j) acc += w[head][j] * bf2f(hb[(size_t)nbr[j] * 256]);

  float v = acc * inv;
  v = v > 0.f ? v : (__expf(v) - 1.f);  // per-layer ELU
  v = v > 0.f ? v : (__expf(v) - 1.f);  // outer final ELU
  fout[(size_t)n * 256 + head * 64 + lane] = v;
}

extern "C" void kernel_launch(void* const* d_in, const int* in_sizes, int n_in,
                              void* d_out, int out_size, void* d_ws, size_t ws_size,
                              hipStream_t stream) {
  (void)in_sizes; (void)n_in; (void)out_size;
  const float* node_feats = (const float*)d_in[0];
  // d_in[1] edge_feats, d_in[2] edge_indices: unused by the reference
  const float* adj = (const float*)d_in[3];
  const float* W0 = (const float*)d_in[4];
  const float* a0 = (const float*)d_in[5];
  const float* W1 = (const float*)d_in[6];
  const float* a1 = (const float*)d_in[7];
  const float* W2 = (const float*)d_in[8];
  const float* a2 = (const float*)d_in[9];

  char* p = (char*)d_ws;
  auto carve = [&](size_t bytes) {
    char* q = p;
    p += (bytes + 255) & ~(size_t)255;
    return q;
  };
  int* csr = (int*)carve((size_t)NNODES * CAP * 4);                        // 3.1 MB
  int* cnt = (int*)carve((size_t)NNODES * 4);                              // 16 KB
  unsigned short* x0 = (unsigned short*)carve((size_t)NNODES * 512 * 2);   // 4 MB
  unsigned short* x = (unsigned short*)carve((size_t)NNODES * 2048 * 2);   // 16 MB
  unsigned short* h = (unsigned short*)carve((size_t)NNODES * 2048 * 2);   // 16 MB (bf16)
  unsigned short* Wt0 = (unsigned short*)carve((size_t)2048 * 512 * 2);    // 2 MB
  unsigned short* Wt1 = (unsigned short*)carve((size_t)2048 * 2048 * 2);   // 8 MB
  unsigned short* Wt2 = (unsigned short*)carve((size_t)256 * 2048 * 2);    // 1 MB
  float* fs = (float*)carve((size_t)NHEADS * NNODES * 4);
  float* fd = (float*)carve((size_t)NHEADS * NNODES * 4);
  float* fps = (float*)carve((size_t)64 * NNODES * 4);                     // 1 MB
  float* fpd = (float*)carve((size_t)64 * NNODES * 4);                     // 1 MB
  float* Cp = (float*)carve((size_t)4 * NNODES * 256 * 4);                 // 16.8 MB (split-K)
  const bool use_sk = (size_t)(p - (char*)d_ws) <= ws_size;                // fallback if ws too small

  // prep: CSR(4096) + cast(2048) + Wt0(256) + Wt1(1024) + Wt2(128) = 7552 blocks
  k_prep<<<7552, 256, 0, stream>>>(adj, csr, cnt, node_feats, x0,
                                   W0, Wt0, W1, Wt1, W2, Wt2);
  // ---- layer 0: K=512, F=512, Ntot=2048 ----
  k_gemm_p<<<(4096 / 128) * (2048 / 256), 512, 0, stream>>>(x0, Wt0, h, a0, fps, fpd,
                                                            4096, 2048, 512);
  k_fred<<<64, 256, 0, stream>>>(fps, fpd, fs, fd);
  k_agg512<<<NHEADS * (NNODES / 4), 256, 0, stream>>>(h, fs, fd, csr, cnt, x);
  // ---- layer 1: K=2048, F=512, Ntot=2048 ----
  k_gemm_p<<<(4096 / 128) * (2048 / 256), 512, 0, stream>>>(x, Wt1, h, a1, fps, fpd,
                                                            4096, 2048, 2048);
  k_fred<<<64, 256, 0, stream>>>(fps, fpd, fs, fd);
  k_agg512<<<NHEADS * (NNODES / 4), 256, 0, stream>>>(h, fs, fd, csr, cnt, x);
  // ---- layer 2: K=2048, F=64, Ntot=256 ----
  if (use_sk) {
    k_gemm_sk<<<4 * (4096 / 128) * (256 / 256), 512, 0, stream>>>(x, Wt2, Cp, 4096, 256, 2048);
    k_l2post<<<NNODES, 256, 0, stream>>>(Cp, h, a2, fs, fd);
  } else {
    k_gemm_plain<<<(4096 / 128) * (256 / 256), 512, 0, stream>>>(x, Wt2, h, 4096, 256, 2048);
    k_f<<<NNODES, 256, 0, stream>>>(h, a2, fs, fd, 64);
  }
  k_agg64<<<NNODES, 256, 0, stream>>>(h, fs, fd, csr, cnt, (float*)d_out);
}

// Round 14
// 184.400 us; speedup vs baseline: 1.0957x; 1.0957x over previous
//
#include <hip/hip_runtime.h>
#include <hip/hip_bf16.h>
#include <stdint.h>

#define NNODES 4096
#define NHEADS 4
#define CAP 192   // max neighbors kept per row (deg ~42, binomial tail << 192)

typedef short s16x8 __attribute__((ext_vector_type(8)));
typedef float f32x4 __attribute__((ext_vector_type(4)));
typedef unsigned int u32x4 __attribute__((ext_vector_type(4)));

typedef const __attribute__((address_space(1))) unsigned short* gas_ushort_p;
typedef __attribute__((address_space(3))) unsigned short* las_ushort_p;

__device__ __forceinline__ unsigned short f2bf(float f) {
  unsigned u = __builtin_bit_cast(unsigned, f);
  u += 0x7FFFu + ((u >> 16) & 1u);   // RNE
  return (unsigned short)(u >> 16);
}
__device__ __forceinline__ float bf2f(unsigned short s) {
  return __builtin_bit_cast(float, ((unsigned)s) << 16);
}
// pack two f32 -> (bf16 lo, bf16 hi)  [guide T12 recipe: no builtin on gfx950]
__device__ __forceinline__ unsigned cvt_pk_bf16(float lo, float hi) {
  unsigned r;
  asm("v_cvt_pk_bf16_f32 %0, %1, %2" : "=v"(r) : "v"(lo), "v"(hi));
  return r;
}
// acc += a.bf16[0]*b.bf16[0] + a.bf16[1]*b.bf16[1]   (VOP3P v_dot2_f32_bf16)
__device__ __forceinline__ float dot2bf(unsigned a, unsigned b, float c) {
  asm("v_dot2_f32_bf16 %0, %1, %2, %0" : "+v"(c) : "v"(a), "v"(b));
  return c;
}

// ================= fused prep: CSR build + cast + 3x weight transpose =================
__global__ __launch_bounds__(256) void k_prep(const float* __restrict__ adj,
                                              int* __restrict__ csr, int* __restrict__ cnt,
                                              const float* __restrict__ node_feats,
                                              unsigned short* __restrict__ x0,
                                              const float* __restrict__ W0,
                                              unsigned short* __restrict__ Wt0,
                                              const float* __restrict__ W1,
                                              unsigned short* __restrict__ Wt1,
                                              const float* __restrict__ W2,
                                              unsigned short* __restrict__ Wt2) {
  __shared__ int wcnt[4];
  __shared__ unsigned short t[64][65];
  const int bid = blockIdx.x;
  const int tid = threadIdx.x;

  if (bid < 4096) {
    // ---- CSR build: one block per row, two-phase ----
    const int row = bid;
    const int wid = tid >> 6;
    const int lane = tid & 63;
    const float4* ar = (const float4*)(adj + (size_t)row * NNODES);
    int* crow = csr + row * CAP;
    const unsigned long long below = (1ull << lane) - 1ull;

    float4 v[4];
#pragma unroll
    for (int it = 0; it < 4; ++it) v[it] = ar[wid * 256 + it * 64 + lane];

    unsigned long long b[4][4];
    int wtotal = 0;
#pragma unroll
    for (int it = 0; it < 4; ++it) {
      b[it][0] = __ballot(v[it].x > 0.f);
      b[it][1] = __ballot(v[it].y > 0.f);
      b[it][2] = __ballot(v[it].z > 0.f);
      b[it][3] = __ballot(v[it].w > 0.f);
      wtotal += __popcll(b[it][0]) + __popcll(b[it][1]) + __popcll(b[it][2]) + __popcll(b[it][3]);
    }
    if (lane == 0) wcnt[wid] = wtotal;
    __syncthreads();

    int base = 0;
#pragma unroll
    for (int w = 0; w < 4; ++w) base += (w < wid) ? wcnt[w] : 0;

#pragma unroll
    for (int it = 0; it < 4; ++it) {
      int pre = __popcll(b[it][0] & below) + __popcll(b[it][1] & below) +
                __popcll(b[it][2] & below) + __popcll(b[it][3] & below);
      int col0 = wid * 1024 + it * 256 + lane * 4;
      int pos = base + pre;
      if (v[it].x > 0.f) { if (pos < CAP) crow[pos] = col0;     ++pos; }
      if (v[it].y > 0.f) { if (pos < CAP) crow[pos] = col0 + 1; ++pos; }
      if (v[it].z > 0.f) { if (pos < CAP) crow[pos] = col0 + 2; ++pos; }
      if (v[it].w > 0.f) { if (pos < CAP) crow[pos] = col0 + 3; ++pos; }
      base += __popcll(b[it][0]) + __popcll(b[it][1]) + __popcll(b[it][2]) + __popcll(b[it][3]);
    }
    if (tid == 0) {
      int total = wcnt[0] + wcnt[1] + wcnt[2] + wcnt[3];
      cnt[row] = total < CAP ? total : CAP;
    }
    return;
  }

  if (bid < 6144) {
    // ---- node_feats f32 -> bf16 ----
    int i = (bid - 4096) * 256 + tid;
    float4 v = ((const float4*)node_feats)[i];
    ushort4 o;
    o.x = f2bf(v.x); o.y = f2bf(v.y); o.z = f2bf(v.z); o.w = f2bf(v.w);
    ((ushort4*)x0)[i] = o;
    return;
  }

  // ---- W [H][K][F] f32 -> Wt [H*F][K] bf16, 64x64 tiles ----
  const float* W;
  unsigned short* Wt;
  int K, F, idx;
  if (bid < 6400) { W = W0; Wt = Wt0; K = 512;  F = 512; idx = bid - 6144; }
  else if (bid < 7424) { W = W1; Wt = Wt1; K = 2048; F = 512; idx = bid - 6400; }
  else { W = W2; Wt = Wt2; K = 2048; F = 64; idx = bid - 7424; }
  const int nk = K >> 6, nf = F >> 6;
  const int h = idx / (nk * nf);
  const int rem = idx % (nk * nf);
  const int kt = rem / nf, ft = rem % nf;
  const float* Wp = W + (size_t)h * K * F;
  for (int it = 0; it < 16; ++it) {
    int j = it * 256 + tid;
    int r = j >> 6, c = j & 63;
    t[c][r] = f2bf(Wp[(size_t)(kt * 64 + r) * F + ft * 64 + c]);
  }
  __syncthreads();
  for (int it = 0; it < 16; ++it) {
    int j = it * 256 + tid;
    int c = j >> 6, r = j & 63;
    Wt[(size_t)(h * F + ft * 64 + c) * K + kt * 64 + r] = t[c][r];
  }
}

// ======== pipelined GEMM, 512 threads / 8 waves (2Mx4N), 128x128 tile, BK=64 ========
// dbuf LDS + counted vmcnt (never drains mid-loop). 4 loads/thread/tile -> vmcnt(4).
// 2 blocks/CU co-resident fill each other's stage/barrier bubbles (R13 lesson:
// 1 block/CU exposes them). Wave owns 64x32: acc[4][2].
// FUSE_F: butterfly transpose-reduce f-partials; slot (tn*4+wn), 16 per head.
template <bool F32OUT, bool FUSE_F>
__device__ __forceinline__ void gemm_body(const unsigned short* __restrict__ A,
                                          const unsigned short* __restrict__ B,
                                          void* __restrict__ Cv,
                                          const float* __restrict__ avec,
                                          float* __restrict__ fps, float* __restrict__ fpd,
                                          int N, int K, int tm, int tn, int k0, int nkt,
                                          unsigned short* sA0, unsigned short* sB0) {
  unsigned short (*sA)[128 * 64] = (unsigned short(*)[128 * 64])sA0;
  unsigned short (*sB)[128 * 64] = (unsigned short(*)[128 * 64])sB0;
  const int tid = threadIdx.x;
  const int lane = tid & 63;
  const int wave = tid >> 6;          // 0..7
  const int wm = wave >> 2;           // 0..1 (64-row half)
  const int wn = wave & 3;            // 0..3 (32-col quarter)

  f32x4 acc[4][2];
#pragma unroll
  for (int i = 0; i < 4; ++i)
#pragma unroll
    for (int j = 0; j < 2; ++j) acc[i][j] = (f32x4){0.f, 0.f, 0.f, 0.f};

  int soff[2], loff[2];               // 1024 x 16B chunks per operand, 2 per thread
#pragma unroll
  for (int it = 0; it < 2; ++it) {
    int cid = it * 512 + tid;
    int r = cid >> 3, cb = cid & 7;
    soff[it] = r * K + ((cb ^ (r & 7)) << 3);   // pre-swizzled global source (ushorts)
    loff[it] = cid << 3;                        // linear LDS dest (ushorts)
  }
  const unsigned short* Ab = A + (size_t)tm * 128 * K + k0;
  const unsigned short* Bb = B + (size_t)tn * 128 * K + k0;

  auto stage = [&](int slot, int ko) {
    const unsigned short* Ag = Ab + (ko << 6);
    const unsigned short* Bg = Bb + (ko << 6);
#pragma unroll
    for (int it = 0; it < 2; ++it)
      __builtin_amdgcn_global_load_lds((gas_ushort_p)(Ag + soff[it]),
                                       (las_ushort_p)(&sA[slot][0]) + loff[it], 16, 0, 0);
#pragma unroll
    for (int it = 0; it < 2; ++it)
      __builtin_amdgcn_global_load_lds((gas_ushort_p)(Bg + soff[it]),
                                       (las_ushort_p)(&sB[slot][0]) + loff[it], 16, 0, 0);
  };

  auto compute = [&](int slot) {
#pragma unroll
    for (int kk = 0; kk < 2; ++kk) {
      s16x8 af[4], bfr[2];
#pragma unroll
      for (int mi = 0; mi < 4; ++mi) {
        int r = wm * 64 + mi * 16 + (lane & 15);
        int kb = (kk << 6) + ((lane >> 4) << 4);
        af[mi] = *(const s16x8*)((const char*)&sA[slot][0] + r * 128 + (kb ^ ((r & 7) << 4)));
      }
#pragma unroll
      for (int ni = 0; ni < 2; ++ni) {
        int r = wn * 32 + ni * 16 + (lane & 15);
        int kb = (kk << 6) + ((lane >> 4) << 4);
        bfr[ni] = *(const s16x8*)((const char*)&sB[slot][0] + r * 128 + (kb ^ ((r & 7) << 4)));
      }
      __builtin_amdgcn_s_setprio(1);
#pragma unroll
      for (int mi = 0; mi < 4; ++mi)
#pragma unroll
        for (int ni = 0; ni < 2; ++ni)
          acc[mi][ni] =
              __builtin_amdgcn_mfma_f32_16x16x32_bf16(af[mi], bfr[ni], acc[mi][ni], 0, 0, 0);
      __builtin_amdgcn_s_setprio(0);
    }
  };

  stage(0, 0);
  if (nkt > 1) stage(1, 1);

  for (int t = 0; t < nkt - 1; ++t) {
    asm volatile("s_waitcnt vmcnt(4)" ::: "memory");   // tile t complete (4 newer in flight)
    __builtin_amdgcn_s_barrier();
    __builtin_amdgcn_sched_barrier(0);
    compute(t & 1);
    __builtin_amdgcn_sched_barrier(0);
    __builtin_amdgcn_s_barrier();
    __builtin_amdgcn_sched_barrier(0);
    if (t + 2 < nkt) stage(t & 1, t + 2);
  }
  asm volatile("s_waitcnt vmcnt(0)" ::: "memory");
  __builtin_amdgcn_s_barrier();
  __builtin_amdgcn_sched_barrier(0);
  compute((nkt - 1) & 1);

  // epilogue: C/D layout col=lane&15, row=(lane>>4)*4+r  [m89-verified]
#pragma unroll
  for (int mi = 0; mi < 4; ++mi) {
    int row0 = tm * 128 + wm * 64 + mi * 16 + ((lane >> 4) << 2);
#pragma unroll
    for (int ni = 0; ni < 2; ++ni) {
      int col = tn * 128 + wn * 32 + ni * 16 + (lane & 15);
#pragma unroll
      for (int r = 0; r < 4; ++r) {
        if constexpr (F32OUT)
          ((float*)Cv)[(size_t)(row0 + r) * N + col] = acc[mi][ni][r];
        else
          ((unsigned short*)Cv)[(size_t)(row0 + r) * N + col] = f2bf(acc[mi][ni][r]);
      }
    }
  }

  if constexpr (FUSE_F) {
    const int head = tn >> 2;
    const int cw = tn * 128 + wn * 32 + (lane & 15) - head * 512;
    float a0v[2], a1v[2];
#pragma unroll
    for (int ni = 0; ni < 2; ++ni) {
      a0v[ni] = avec[head * 1024 + cw + ni * 16];
      a1v[ni] = avec[head * 1024 + 512 + cw + ni * 16];
    }
    float s16v[16], d16v[16];
#pragma unroll
    for (int mi = 0; mi < 4; ++mi)
#pragma unroll
      for (int r = 0; r < 4; ++r) {
        float vs = 0.f, vd = 0.f;
#pragma unroll
        for (int ni = 0; ni < 2; ++ni) {
          float av = acc[mi][ni][r];
          vs += av * a0v[ni];
          vd += av * a1v[ni];
        }
        s16v[mi * 4 + r] = vs;
        d16v[mi * 4 + r] = vd;
      }
    // butterfly transpose-reduce across the 16 col-lanes (lane&15)
    const bool q0 = lane & 1, q1 = lane & 2, q2 = lane & 4, q3 = lane & 8;
    float s8[8], d8[8];
#pragma unroll
    for (int j = 0; j < 8; ++j) {
      float ms = q0 ? s16v[j + 8] : s16v[j], ss = q0 ? s16v[j] : s16v[j + 8];
      s8[j] = ms + __shfl_xor(ss, 1);
      float md = q0 ? d16v[j + 8] : d16v[j], sd = q0 ? d16v[j] : d16v[j + 8];
      d8[j] = md + __shfl_xor(sd, 1);
    }
    float s4[4], d4[4];
#pragma unroll
    for (int j = 0; j < 4; ++j) {
      float ms = q1 ? s8[j + 4] : s8[j], ss = q1 ? s8[j] : s8[j + 4];
      s4[j] = ms + __shfl_xor(ss, 2);
      float md = q1 ? d8[j + 4] : d8[j], sd = q1 ? d8[j] : d8[j + 4];
      d4[j] = md + __shfl_xor(sd, 2);
    }
    float s2v[2], d2v[2];
#pragma unroll
    for (int j = 0; j < 2; ++j) {
      float ms = q2 ? s4[j + 2] : s4[j], ss = q2 ? s4[j] : s4[j + 2];
      s2v[j] = ms + __shfl_xor(ss, 4);
      float md = q2 ? d4[j + 2] : d4[j], sd = q2 ? d4[j] : d4[j + 2];
      d2v[j] = md + __shfl_xor(sd, 4);
    }
    float ms = q3 ? s2v[1] : s2v[0], ss = q3 ? s2v[0] : s2v[1];
    float s1v = ms + __shfl_xor(ss, 8);
    float md = q3 ? d2v[1] : d2v[0], sd = q3 ? d2v[0] : d2v[1];
    float d1v = md + __shfl_xor(sd, 8);
    // lane holds value idx = bitrev4(lane&15)
    int idx = ((lane & 1) << 3) | ((lane & 2) << 1) | ((lane & 4) >> 1) | ((lane & 8) >> 3);
    int row = tm * 128 + wm * 64 + (idx >> 2) * 16 + ((lane >> 4) << 2) + (idx & 3);
    fps[(tn * 4 + wn) * NNODES + row] = s1v;
    fpd[(tn * 4 + wn) * NNODES + row] = d1v;
  }
}

// XCD-pinned tile mapping for 512-block grids (ntile=16): XCD x (= bid&7 under
// round-robin dispatch) owns tn-pair {2x,2x+1} -> its B-panel stays L2-resident.
// Pure bijection: correctness independent of actual dispatch mapping.
__device__ __forceinline__ void tile_map(int bid, int ntile, int& tm, int& tn) {
  if (ntile == 16) {
    int xcd = bid & 7, idx = bid >> 3;
    tn = xcd * 2 + (idx & 1);
    tm = idx >> 1;
  } else {
    tm = bid / ntile;
    tn = bid % ntile;
  }
}

__global__ __launch_bounds__(512, 4) void k_gemm_p(const unsigned short* __restrict__ A,
                                                   const unsigned short* __restrict__ B,
                                                   unsigned short* __restrict__ C,
                                                   const float* __restrict__ avec,
                                                   float* __restrict__ fps,
                                                   float* __restrict__ fpd,
                                                   int M, int N, int K) {
  __shared__ __align__(16) unsigned short sA[2][128 * 64];
  __shared__ __align__(16) unsigned short sB[2][128 * 64];
  int tm, tn;
  tile_map(blockIdx.x, N >> 7, tm, tn);
  gemm_body<false, true>(A, B, C, avec, fps, fpd, N, K, tm, tn, 0, K >> 6,
                         &sA[0][0], &sB[0][0]);
}

// plain (no f-fusion) variant for the non-split-K fallback
__global__ __launch_bounds__(512, 4) void k_gemm_plain(const unsigned short* __restrict__ A,
                                                       const unsigned short* __restrict__ B,
                                                       unsigned short* __restrict__ C,
                                                       int M, int N, int K) {
  __shared__ __align__(16) unsigned short sA[2][128 * 64];
  __shared__ __align__(16) unsigned short sB[2][128 * 64];
  int tm, tn;
  tile_map(blockIdx.x, N >> 7, tm, tn);
  gemm_body<false, false>(A, B, C, nullptr, nullptr, nullptr, N, K, tm, tn, 0, K >> 6,
                          &sA[0][0], &sB[0][0]);
}

// split-K (x4) variant: writes f32 partials to Cp[kc][M][N]
__global__ __launch_bounds__(512, 4) void k_gemm_sk(const unsigned short* __restrict__ A,
                                                    const unsigned short* __restrict__ B,
                                                    float* __restrict__ Cp,
                                                    int M, int N, int K) {
  __shared__ __align__(16) unsigned short sA[2][128 * 64];
  __shared__ __align__(16) unsigned short sB[2][128 * 64];
  const int ntile = N >> 7;
  const int tpk = (M >> 7) * ntile;       // tiles per K-chunk
  const int kc = blockIdx.x / tpk;
  const int rest = blockIdx.x % tpk;
  const int tm = rest / ntile, tn = rest % ntile;
  const int KC = K >> 2;
  gemm_body<true, false>(A, B, Cp + (size_t)kc * M * N, nullptr, nullptr, nullptr,
                         N, K, tm, tn, kc * KC, KC >> 6, &sA[0][0], &sB[0][0]);
}

// reduce f partials: fs[head][n] = sum_{j<16} fps[(head*16+j)][n]
__global__ __launch_bounds__(256) void k_fred(const float* __restrict__ fps,
                                              const float* __restrict__ fpd,
                                              float* __restrict__ fs,
                                              float* __restrict__ fd) {
  int t = blockIdx.x * 256 + threadIdx.x;   // 16384 threads
  int head = t >> 12, n = t & 4095;
  float s = 0.f, d = 0.f;
#pragma unroll
  for (int j = 0; j < 16; ++j) {
    s += fps[(head * 16 + j) * NNODES + n];
    d += fpd[(head * 16 + j) * NNODES + n];
  }
  fs[head * NNODES + n] = s;
  fd[head * NNODES + n] = d;
}

// ---- layer-2 post: reduce 4 split-K partials -> h bf16, and fs/fd from f32 sums ----
__global__ __launch_bounds__(256) void k_l2post(const float* __restrict__ Cp,
                                                unsigned short* __restrict__ h,
                                                const float* __restrict__ a2,
                                                float* __restrict__ fs,
                                                float* __restrict__ fd) {
  const int n = blockIdx.x;
  const int tid = threadIdx.x;
  const int MN = NNODES * 256;
  const int base = n * 256 + tid;
  float s0 = Cp[base], s1 = Cp[base + MN], s2 = Cp[base + 2 * MN], s3 = Cp[base + 3 * MN];
  float s = (s0 + s1) + (s2 + s3);
  h[(size_t)base] = f2bf(s);
  const int head = tid >> 6, lane = tid & 63;
  float vs = s * a2[head * 128 + lane];
  float vd = s * a2[head * 128 + 64 + lane];
#pragma unroll
  for (int off = 32; off; off >>= 1) {
    vs += __shfl_xor(vs, off);
    vd += __shfl_xor(vd, off);
  }
  if (lane == 0) {
    fs[head * NNODES + n] = vs;
    fd[head * NNODES + n] = vd;
  }
}

// ---------------- f_src / f_dst (fallback only, F=64); h is bf16 ----------------
__global__ __launch_bounds__(256) void k_f(const unsigned short* __restrict__ h,
                                           const float* __restrict__ a,
                                           float* __restrict__ fs, float* __restrict__ fd,
                                           int F) {
  const int n = blockIdx.x;
  const int head = threadIdx.x >> 6;
  const int lane = threadIdx.x & 63;
  const unsigned short* hp = h + (size_t)n * (F * 4) + head * F;
  const float* a0 = a + head * 2 * F;
  const float* a1 = a0 + F;
  float x = bf2f(hp[lane]);
  float s0 = x * a0[lane];
  float s1 = x * a1[lane];
#pragma unroll
  for (int off = 32; off; off >>= 1) {
    s0 += __shfl_xor(s0, off);
    s1 += __shfl_xor(s1, off);
  }
  if (lane == 0) {
    fs[head * NNODES + n] = s0;
    fd[head * NNODES + n] = s1;
  }
}

// ------- sparse softmax + aggregate, F=512, XCD-pinned heads, 16-deep gather -------
__global__ __launch_bounds__(256) void k_agg512(const unsigned short* __restrict__ h,
                                                const float* __restrict__ fs,
                                                const float* __restrict__ fd,
                                                const int* __restrict__ csr,
                                                const int* __restrict__ cnt,
                                                unsigned short* __restrict__ xout) {
  const int g = blockIdx.x >> 3;
  const int x8 = blockIdx.x & 7;
  const int head = x8 >> 1;               // XCD pair -> head
  const int ng = g * 2 + (x8 & 1);        // 0..1023
  const int wid = threadIdx.x >> 6;
  const int lane = threadIdx.x & 63;
  const int n = ng * 4 + wid;
  __shared__ __align__(16) float ws[4][CAP];   // unnormalized softmax weights
  __shared__ __align__(16) int os[4][CAP];     // neighbor row byte offsets (m<<12)
  const int deg = cnt[n];
  const int deg16 = (deg + 15) & ~15;
  const int* nbr = csr + n * CAP;
  const float fsv = fs[head * NNODES + n];
  const float* fdh = fd + head * NNODES;

  // ---- softmax phase: up to 3 edges per lane in registers ----
  float p[3];
  int mm[3];
  float mx = -1e30f;
#pragma unroll
  for (int r = 0; r < 3; ++r) {
    int j = lane + r * 64;
    bool valid = j < deg;
    mm[r] = valid ? nbr[j] : 0;
    float s = fsv + fdh[mm[r]];
    s = s > 0.f ? s : 0.2f * s;  // leaky_relu(0.2)
    p[r] = valid ? s : -1e30f;
    mx = fmaxf(mx, p[r]);
  }
#pragma unroll
  for (int off = 32; off; off >>= 1) mx = fmaxf(mx, __shfl_xor(mx, off));
  float sum = 0.f;
#pragma unroll
  for (int r = 0; r < 3; ++r) {
    int j = lane + r * 64;
    float pv = (j < deg) ? __expf(p[r] - mx) : 0.f;
    sum += pv;
    if (j < deg16) {            // zero-pad up to deg16 (row 0, weight 0)
      ws[wid][j] = pv;
      os[wid][j] = mm[r] << 12;  // row byte offset in h (2048 ushorts = 4096 B)
    }
  }
#pragma unroll
  for (int off = 32; off; off >>= 1) sum += __shfl_xor(sum, off);
  const float inv = 1.f / sum;  // folded into epilogue

  // ---- gather phase: 16 rows in flight, perm+dot2 row-pairs ----
  float acc[8];
#pragma unroll
  for (int i = 0; i < 8; ++i) acc[i] = 0.f;
  const char* hb = (const char*)(h + head * 512) + lane * 16;  // head's 1KB segment

  for (int jb = 0; jb < deg16; jb += 16) {
    float4 w0 = *(const float4*)&ws[wid][jb];
    float4 w1 = *(const float4*)&ws[wid][jb + 4];
    float4 w2 = *(const float4*)&ws[wid][jb + 8];
    float4 w3 = *(const float4*)&ws[wid][jb + 12];
    int4 o0 = *(const int4*)&os[wid][jb];
    int4 o1 = *(const int4*)&os[wid][jb + 4];
    int4 o2 = *(const int4*)&os[wid][jb + 8];
    int4 o3 = *(const int4*)&os[wid][jb + 12];
    u32x4 v[16];
    v[0]  = *(const u32x4*)(hb + o0.x);
    v[1]  = *(const u32x4*)(hb + o0.y);
    v[2]  = *(const u32x4*)(hb + o0.z);
    v[3]  = *(const u32x4*)(hb + o0.w);
    v[4]  = *(const u32x4*)(hb + o1.x);
    v[5]  = *(const u32x4*)(hb + o1.y);
    v[6]  = *(const u32x4*)(hb + o1.z);
    v[7]  = *(const u32x4*)(hb + o1.w);
    v[8]  = *(const u32x4*)(hb + o2.x);
    v[9]  = *(const u32x4*)(hb + o2.y);
    v[10] = *(const u32x4*)(hb + o2.z);
    v[11] = *(const u32x4*)(hb + o2.w);
    v[12] = *(const u32x4*)(hb + o3.x);
    v[13] = *(const u32x4*)(hb + o3.y);
    v[14] = *(const u32x4*)(hb + o3.z);
    v[15] = *(const u32x4*)(hb + o3.w);
    unsigned pw[8];
    pw[0] = cvt_pk_bf16(w0.x, w0.y);
    pw[1] = cvt_pk_bf16(w0.z, w0.w);
    pw[2] = cvt_pk_bf16(w1.x, w1.y);
    pw[3] = cvt_pk_bf16(w1.z, w1.w);
    pw[4] = cvt_pk_bf16(w2.x, w2.y);
    pw[5] = cvt_pk_bf16(w2.z, w2.w);
    pw[6] = cvt_pk_bf16(w3.x, w3.y);
    pw[7] = cvt_pk_bf16(w3.z, w3.w);
#pragma unroll
    for (int rp = 0; rp < 8; ++rp) {
      u32x4 a = v[2 * rp], b = v[2 * rp + 1];
      unsigned wp = pw[rp];
#pragma unroll
      for (int q = 0; q < 4; ++q) {
        unsigned lo = __builtin_amdgcn_perm(b[q], a[q], 0x05040100u);
        unsigned hi = __builtin_amdgcn_perm(b[q], a[q], 0x07060302u);
        acc[2 * q] = dot2bf(wp, lo, acc[2 * q]);
        acc[2 * q + 1] = dot2bf(wp, hi, acc[2 * q + 1]);
      }
    }
  }

  s16x8 o;
#pragma unroll
  for (int i = 0; i < 8; ++i) {
    float v = acc[i] * inv;
    v = v > 0.f ? v : (__expf(v) - 1.f);  // per-layer ELU
    o[i] = (short)f2bf(v);
  }
  *(s16x8*)(xout + (size_t)n * 2048 + head * 512 + lane * 8) = o;
}

// ---------------- final layer aggregate (F=64) + double ELU, f32 out ----------------
__global__ __launch_bounds__(256) void k_agg64(const unsigned short* __restrict__ h,
                                               const float* __restrict__ fs,
                                               const float* __restrict__ fd,
                                               const int* __restrict__ csr,
                                               const int* __restrict__ cnt,
                                               float* __restrict__ fout) {
  const int n = blockIdx.x;
  const int head = threadIdx.x >> 6;
  const int lane = threadIdx.x & 63;
  __shared__ float w[NHEADS][CAP];
  const int deg = cnt[n];
  const int* nbr = csr + n * CAP;
  const float fsv = fs[head * NNODES + n];
  const float* fdh = fd + head * NNODES;

  float mx = -1e30f;
  for (int j = lane; j < deg; j += 64) {
    float s = fsv + fdh[nbr[j]];
    s = s > 0.f ? s : 0.2f * s;
    w[head][j] = s;
    mx = fmaxf(mx, s);
  }
#pragma unroll
  for (int off = 32; off; off >>= 1) mx = fmaxf(mx, __shfl_xor(mx, off));
  float sum = 0.f;
  for (int j = lane; j < deg; j += 64) {
    float pv = __expf(w[head][j] - mx);
    w[head][j] = pv;
    sum += pv;
  }
#pragma unroll
  for (int off = 32; off; off >>= 1) sum += __shfl_xor(sum, off);
  const float inv = 1.f / sum;

  float acc = 0.f;
  const unsigned short* hb = h + head * 64 + lane;
  int j = 0;
  for (; j + 3 < deg; j += 4) {
    int m0 = nbr[j], m1 = nbr[j + 1], m2 = nbr[j + 2], m3 = nbr[j + 3];
    float w0 = w[head][j], w1 = w[head][j + 1], w2 = w[head][j + 2], w3 = w[head][j + 3];
    acc += w0 * bf2f(hb[(size_t)m0 * 256]) + w1 * bf2f(hb[(size_t)m1 * 256]) +
           w2 * bf2f(hb[(size_t)m2 * 256]) + w3 * bf2f(hb[(size_t)m3 * 256]);
  }
  for (; j < deg; ++j) acc += w[head][j] * bf2f(hb[(size_t)nbr[j] * 256]);

  float v = acc * inv;
  v = v > 0.f ? v : (__expf(v) - 1.f);  // per-layer ELU
  v = v > 0.f ? v : (__expf(v) - 1.f);  // outer final ELU
  fout[(size_t)n * 256 + head * 64 + lane] = v;
}

extern "C" void kernel_launch(void* const* d_in, const int* in_sizes, int n_in,
                              void* d_out, int out_size, void* d_ws, size_t ws_size,
                              hipStream_t stream) {
  (void)in_sizes; (void)n_in; (void)out_size;
  const float* node_feats = (const float*)d_in[0];
  // d_in[1] edge_feats, d_in[2] edge_indices: unused by the reference
  const float* adj = (const float*)d_in[3];
  const float* W0 = (const float*)d_in[4];
  const float* a0 = (const float*)d_in[5];
  const float* W1 = (const float*)d_in[6];
  const float* a1 = (const float*)d_in[7];
  const float* W2 = (const float*)d_in[8];
  const float* a2 = (const float*)d_in[9];

  char* p = (char*)d_ws;
  auto carve = [&](size_t bytes) {
    char* q = p;
    p += (bytes + 255) & ~(size_t)255;
    return q;
  };
  int* csr = (int*)carve((size_t)NNODES * CAP * 4);                        // 3.1 MB
  int* cnt = (int*)carve((size_t)NNODES * 4);                              // 16 KB
  unsigned short* x0 = (unsigned short*)carve((size_t)NNODES * 512 * 2);   // 4 MB
  unsigned short* x = (unsigned short*)carve((size_t)NNODES * 2048 * 2);   // 16 MB
  unsigned short* h = (unsigned short*)carve((size_t)NNODES * 2048 * 2);   // 16 MB (bf16)
  unsigned short* Wt0 = (unsigned short*)carve((size_t)2048 * 512 * 2);    // 2 MB
  unsigned short* Wt1 = (unsigned short*)carve((size_t)2048 * 2048 * 2);   // 8 MB
  unsigned short* Wt2 = (unsigned short*)carve((size_t)256 * 2048 * 2);    // 1 MB
  float* fs = (float*)carve((size_t)NHEADS * NNODES * 4);
  float* fd = (float*)carve((size_t)NHEADS * NNODES * 4);
  float* fps = (float*)carve((size_t)64 * NNODES * 4);                     // 1 MB
  float* fpd = (float*)carve((size_t)64 * NNODES * 4);                     // 1 MB
  float* Cp = (float*)carve((size_t)4 * NNODES * 256 * 4);                 // 16.8 MB (split-K)
  const bool use_sk = (size_t)(p - (char*)d_ws) <= ws_size;                // fallback if ws too small

  // prep: CSR(4096) + cast(2048) + Wt0(256) + Wt1(1024) + Wt2(128) = 7552 blocks
  k_prep<<<7552, 256, 0, stream>>>(adj, csr, cnt, node_feats, x0,
                                   W0, Wt0, W1, Wt1, W2, Wt2);
  // ---- layer 0: K=512, F=512, Ntot=2048 ----
  k_gemm_p<<<(4096 / 128) * (2048 / 128), 512, 0, stream>>>(x0, Wt0, h, a0, fps, fpd,
                                                            4096, 2048, 512);
  k_fred<<<64, 256, 0, stream>>>(fps, fpd, fs, fd);
  k_agg512<<<NHEADS * (NNODES / 4), 256, 0, stream>>>(h, fs, fd, csr, cnt, x);
  // ---- layer 1: K=2048, F=512, Ntot=2048 ----
  k_gemm_p<<<(4096 / 128) * (2048 / 128), 512, 0, stream>>>(x, Wt1, h, a1, fps, fpd,
                                                            4096, 2048, 2048);
  k_fred<<<64, 256, 0, stream>>>(fps, fpd, fs, fd);
  k_agg512<<<NHEADS * (NNODES / 4), 256, 0, stream>>>(h, fs, fd, csr, cnt, x);
  // ---- layer 2: K=2048, F=64, Ntot=256 ----
  if (use_sk) {
    k_gemm_sk<<<4 * (4096 / 128) * (256 / 128), 512, 0, stream>>>(x, Wt2, Cp, 4096, 256, 2048);
    k_l2post<<<NNODES, 256, 0, stream>>>(Cp, h, a2, fs, fd);
  } else {
    k_gemm_plain<<<(4096 / 128) * (256 / 128), 512, 0, stream>>>(x, Wt2, h, 4096, 256, 2048);
    k_f<<<NNODES, 256, 0, stream>>>(h, a2, fs, fd, 64);
  }
  k_agg64<<<NNODES, 256, 0, stream>>>(h, fs, fd, csr, cnt, (float*)d_out);
}